// Round 10
// baseline (280.347 us; speedup 1.0000x reference)
//
#include <hip/hip_runtime.h>

typedef unsigned short u16;
typedef unsigned int u32;
typedef __attribute__((ext_vector_type(8))) short bf16x8;
typedef __attribute__((ext_vector_type(4))) float f32x4;

#define MFMA(a,b,c) __builtin_amdgcn_mfma_f32_16x16x32_bf16(a,b,c,0,0,0)

__device__ __forceinline__ float b2f(u16 u){
  union { unsigned int i; float f; } v; v.i = ((unsigned int)u)<<16; return v.f;
}
__device__ __forceinline__ u16 f2b(float f){
  union { float f; unsigned int i; } v; v.f = f;
  unsigned int r = (v.i + 0x7FFFu + ((v.i>>16)&1u))>>16;
  return (u16)r;
}
// async global->LDS, 16B per lane; lds dest must be wave-uniform base (HW adds lane*16)
__device__ __forceinline__ void gld16(const u16* g, u16* l){
  __builtin_amdgcn_global_load_lds((const __attribute__((address_space(1))) u32*)g,
                                   (__attribute__((address_space(3))) u32*)l, 16, 0, 0);
}

// ---------------- combined: time-shift prep (blocks 0..1023) + 4 weight transposes ----------------
__global__ __launch_bounds__(256) void k_pre(
    const float* __restrict__ x,
    const float* __restrict__ Wq, const float* __restrict__ Wk,
    const float* __restrict__ Wv, const float* __restrict__ Wo,
    u16* __restrict__ xs, u16* __restrict__ WT, u16* __restrict__ WoT)
{
  int bid = blockIdx.x;
  int tid = threadIdx.x;
  if (bid < 1024){
    int idx = bid*256 + tid;                 // one thread per 8 elements
    size_t e = (size_t)idx*8;
    int c = (int)(e & 1023);
    int t = (int)((e>>10)&1023);
    float4 f0 = {0.f,0.f,0.f,0.f}, f1 = {0.f,0.f,0.f,0.f};
    const float* src = nullptr;
    if (c < 512){ if (t > 0) src = x + e - 1024; }
    else        { src = x + e; }
    if (src){ f0 = *(const float4*)src; f1 = *(const float4*)(src+4); }
    u16 o[8];
    o[0]=f2b(f0.x); o[1]=f2b(f0.y); o[2]=f2b(f0.z); o[3]=f2b(f0.w);
    o[4]=f2b(f1.x); o[5]=f2b(f1.y); o[6]=f2b(f1.z); o[7]=f2b(f1.w);
    *(uint4*)(xs + e) = *(const uint4*)o;
    return;
  }
  int z  = (bid-1024)>>8;                    // 0..3 : Wq,Wk,Wv,Wo
  int rc = (bid-1024)&255;
  const float* src = (z==0)?Wq:((z==1)?Wk:((z==2)?Wv:Wo));
  u16* dst = (z==3)? WoT : (WT + (size_t)z*1048576);
  int c0 = (rc&15)*64, r0 = (rc>>4)*64;
  __shared__ u16 tile[64][72];
  int r = tid>>2, cc = (tid&3)*16;
  const float* sp = src + (size_t)(r0+r)*1024 + c0+cc;
  float4 a0 = *(const float4*)(sp);
  float4 a1 = *(const float4*)(sp+4);
  float4 a2 = *(const float4*)(sp+8);
  float4 a3 = *(const float4*)(sp+12);
  tile[r][cc+0]=f2b(a0.x); tile[r][cc+1]=f2b(a0.y); tile[r][cc+2]=f2b(a0.z); tile[r][cc+3]=f2b(a0.w);
  tile[r][cc+4]=f2b(a1.x); tile[r][cc+5]=f2b(a1.y); tile[r][cc+6]=f2b(a1.z); tile[r][cc+7]=f2b(a1.w);
  tile[r][cc+8]=f2b(a2.x); tile[r][cc+9]=f2b(a2.y); tile[r][cc+10]=f2b(a2.z); tile[r][cc+11]=f2b(a2.w);
  tile[r][cc+12]=f2b(a3.x); tile[r][cc+13]=f2b(a3.y); tile[r][cc+14]=f2b(a3.z); tile[r][cc+15]=f2b(a3.w);
  __syncthreads();
  int c = tid>>2, rr = (tid&3)*16;
  uint4 o0,o1; u16* p0=(u16*)&o0; u16* p1=(u16*)&o1;
  #pragma unroll
  for (int i=0;i<8;i++){ p0[i]=tile[rr+i][c]; p1[i]=tile[rr+8+i][c]; }
  *(uint4*)(dst + (size_t)(c0+c)*1024 + r0+rr)   = o0;
  *(uint4*)(dst + (size_t)(c0+c)*1024 + r0+rr+8) = o1;
}

// ---------------- QKV GEMM 128x64 tiles (global_load_lds) + fused RoPE; v -> (b,h,d,t) ----------------
// grid (48, 16): n0=bx*64 (64-aligned => which,h uniform per block)
__global__ __launch_bounds__(256) void k_gemm_qkv(
    const u16* __restrict__ A, const u16* __restrict__ Bt,
    const float* __restrict__ bq, const float* __restrict__ bk, const float* __restrict__ bv,
    u16* __restrict__ qb, u16* __restrict__ kb, u16* __restrict__ vT)
{
  __shared__ u16 As[128*32];     // unpadded: required by global_load_lds lane order
  __shared__ u16 Bs[64*32];
  const int n0 = blockIdx.x*64, m0 = blockIdx.y*128;
  const int tid = threadIdx.x, lane = tid&63, wave = tid>>6;
  const int quad = lane>>4, l16 = lane&15;
  const int wm = (wave>>1)*64, wn = (wave&1)*32;
  f32x4 zero = {0.f,0.f,0.f,0.f};
  f32x4 acc[4][2];
  #pragma unroll
  for (int i=0;i<4;i++){ acc[i][0]=zero; acc[i][1]=zero; }
  const int srow = (lane>>2), scol = (lane&3)*8;
  const u16* pa0 = A  + (size_t)(m0 + wave*16 + srow)*1024 + scol;
  const u16* pb0 = Bt + (size_t)(n0 + wave*16 + srow)*1024 + scol;
  u16* lA0 = &As[(wave*16)*32];
  u16* lA1 = &As[(64 + wave*16)*32];
  u16* lB0 = &Bs[(wave*16)*32];
  for (int k0=0;k0<1024;k0+=32){
    __syncthreads();
    gld16(pa0 + k0,           lA0);
    gld16(pa0 + 64*1024 + k0, lA1);
    gld16(pb0 + k0,           lB0);
    __syncthreads();
    bf16x8 af[4], bfr[2];
    #pragma unroll
    for (int mt=0;mt<4;mt++) af[mt]  = *(const bf16x8*)&As[(wm+mt*16+l16)*32 + quad*8];
    #pragma unroll
    for (int nt=0;nt<2;nt++) bfr[nt] = *(const bf16x8*)&Bs[(wn+nt*16+l16)*32 + quad*8];
    #pragma unroll
    for (int mt=0;mt<4;mt++){
      acc[mt][0] = MFMA(af[mt], bfr[0], acc[mt][0]);
      acc[mt][1] = MFMA(af[mt], bfr[1], acc[mt][1]);
    }
  }
  const int which = n0>>10;            // uniform per block
  const int nn0 = (n0 & 1023) + wn;
  const int h = (n0 & 1023)>>6;
  const float* barr = (which==0)?bq:((which==1)?bk:bv);
  float bias0 = barr[nn0 + l16];
  float bias1 = barr[nn0 + 16 + l16];
  if (which == 2){
    // v: write transposed (b,h,d,t): vT[bh*65536 + d*1024 + t]
    #pragma unroll
    for (int mt=0;mt<4;mt++)
      #pragma unroll
      for (int r=0;r<4;r++){
        int m = m0 + wm + mt*16 + quad*4 + r;
        int bb = m>>10, t = m&1023;
        size_t base = (size_t)(bb*16+h)*65536 + t;
        int d0 = wn + l16;
        vT[base + (size_t)d0*1024]      = f2b(acc[mt][0][r] + bias0);
        vT[base + (size_t)(d0+16)*1024] = f2b(acc[mt][1][r] + bias1);
      }
  } else {
    const float scale = (which==0)?0.125f:1.0f;
    u16* dst = (which==0)? qb : kb;
    if (wn == 0){
      const float e = exp2f(-0.625f*(float)l16);
      #pragma unroll
      for (int mt=0;mt<4;mt++)
        #pragma unroll
        for (int r=0;r<4;r++){
          int m = m0 + wm + mt*16 + quad*4 + r;
          int bb = m>>10, t = m&1023;
          float f = (float)t * e;
          float cs = cosf(f), sn = sinf(f);
          float x0 = acc[mt][0][r] + bias0;
          float x1 = acc[mt][1][r] + bias1;
          float v0 = (x0*cs - x1*sn)*scale;
          float v1 = (x1*cs + x0*sn)*scale;
          size_t ob = (((size_t)(bb*16+h))*1024 + (size_t)t)*64 + l16;
          dst[ob]    = f2b(v0);
          dst[ob+16] = f2b(v1);
        }
    } else {
      #pragma unroll
      for (int mt=0;mt<4;mt++)
        #pragma unroll
        for (int r=0;r<4;r++){
          int m = m0 + wm + mt*16 + quad*4 + r;
          int bb = m>>10, t = m&1023;
          float v2 = (acc[mt][0][r] + bias0)*scale;
          float v3 = (acc[mt][1][r] + bias1)*scale;
          size_t ob = (((size_t)(bb*16+h))*1024 + (size_t)t)*64 + 32 + l16;
          dst[ob]    = f2b(v2);
          dst[ob+16] = f2b(v3);
        }
    }
  }
}

// ---------------- output GEMM 64x64 tiles: + bo, x gamma[t], f32 out ----------------
// grid (16, 32) = 512 blocks (2/CU for inter-block overlap)
__global__ __launch_bounds__(256) void k_gemm_out(
    const u16* __restrict__ A, const u16* __restrict__ Bt,
    const float* __restrict__ bo, const float* __restrict__ gamma, float* __restrict__ out)
{
  __shared__ u16 As[64*32];
  __shared__ u16 Bs[64*32];
  const int n0 = blockIdx.x*64, m0 = blockIdx.y*64;
  const int tid = threadIdx.x, lane = tid&63, wave = tid>>6;
  const int quad = lane>>4, l16 = lane&15;
  const int wm = (wave>>1)*32, wn = (wave&1)*32;
  f32x4 zero = {0.f,0.f,0.f,0.f};
  f32x4 acc[2][2];
  #pragma unroll
  for (int i=0;i<2;i++){ acc[i][0]=zero; acc[i][1]=zero; }
  const int srow = (lane>>2), scol = (lane&3)*8;
  const u16* pa0 = A  + (size_t)(m0 + wave*16 + srow)*1024 + scol;
  const u16* pb0 = Bt + (size_t)(n0 + wave*16 + srow)*1024 + scol;
  u16* lA0 = &As[(wave*16)*32];
  u16* lB0 = &Bs[(wave*16)*32];
  for (int k0=0;k0<1024;k0+=32){
    __syncthreads();
    gld16(pa0 + k0, lA0);
    gld16(pb0 + k0, lB0);
    __syncthreads();
    bf16x8 af[2], bfr[2];
    #pragma unroll
    for (int mt=0;mt<2;mt++) af[mt]  = *(const bf16x8*)&As[(wm+mt*16+l16)*32 + quad*8];
    #pragma unroll
    for (int nt=0;nt<2;nt++) bfr[nt] = *(const bf16x8*)&Bs[(wn+nt*16+l16)*32 + quad*8];
    #pragma unroll
    for (int mt=0;mt<2;mt++){
      acc[mt][0] = MFMA(af[mt], bfr[0], acc[mt][0]);
      acc[mt][1] = MFMA(af[mt], bfr[1], acc[mt][1]);
    }
  }
  #pragma unroll
  for (int nt=0;nt<2;nt++){
    int colg = n0 + wn + nt*16 + l16;
    float bias = bo[colg];
    #pragma unroll
    for (int mt=0;mt<2;mt++)
      #pragma unroll
      for (int r=0;r<4;r++){
        int m = m0 + wm + mt*16 + quad*4 + r;
        int t = m&1023;
        float val = (acc[mt][nt][r] + bias)*gamma[t];
        out[(size_t)m*1024 + colg] = val;
      }
  }
}

// ---------------- fused softmax+weight: S in registers, stats in LDS, coalesced P store ----------------
// grid (tb=16, h=16, b=2); 1024 threads = 16 waves = 4 wt x 4 ws; full 64t x 1024s S tile in regs
// P layout: [b][t][h][s]
__global__ __launch_bounds__(1024) void k_sm(
    const u16* __restrict__ q, const u16* __restrict__ k,
    const float* __restrict__ tw, const float* __restrict__ alpha, const float* __restrict__ beta,
    u16* __restrict__ P)
{
  const int tb = blockIdx.x, h = blockIdx.y, b = blockIdx.z;
  const int t0b = tb*64;
  const int tid = threadIdx.x;
  const int wave = tid>>6, lane = tid&63, quad = lane>>4, l16 = lane&15;
  const int wt = wave>>2, ws = wave&3;

  __shared__ u16 qs[64*76];      // q tile, padded rows
  __shared__ u16 ks[256*76];     // K chunk, padded rows; reused as P bounce (64x264) after MFMAs
  __shared__ float tws[1024];
  __shared__ float als[1024];
  __shared__ float pm[4][64];
  __shared__ float pl[4][64];
  __shared__ float fm[64];
  __shared__ float fr[64];

  const size_t bh = (size_t)(b*16+h)*65536;
  const u16* qp = q + bh;
  const u16* kp = k + bh;

  if (tid < 512){
    int row = tid>>3, g = tid&7;
    *(uint4*)&qs[row*76 + g*8] = *(const uint4*)(qp + (size_t)(t0b+row)*64 + g*8);
  }
  tws[tid] = tw[h*1024 + tid];
  als[tid] = alpha[h*1024 + tid];
  __syncthreads();

  bf16x8 qf0 = *(const bf16x8*)&qs[(wt*16+l16)*76 + quad*8];
  bf16x8 qf1 = *(const bf16x8*)&qs[(wt*16+l16)*76 + quad*8 + 32];

  f32x4 acc[16];
  #pragma unroll
  for (int i=0;i<16;i++){ acc[i][0]=0.f; acc[i][1]=0.f; acc[i][2]=0.f; acc[i][3]=0.f; }

  #pragma unroll
  for (int c=0;c<4;c++){
    if (c) __syncthreads();
    {
      int row = tid>>3, g = tid&7;
      *(uint4*)&ks[row*76 + g*8]       = *(const uint4*)(kp + (size_t)(c*256+row)*64 + g*8);
      *(uint4*)&ks[(row+128)*76 + g*8] = *(const uint4*)(kp + (size_t)(c*256+row+128)*64 + g*8);
    }
    __syncthreads();
    #pragma unroll
    for (int j=0;j<4;j++){
      int lt = j*4 + ws;
      bf16x8 kf0 = *(const bf16x8*)&ks[(lt*16+l16)*76 + quad*8];
      bf16x8 kf1 = *(const bf16x8*)&ks[(lt*16+l16)*76 + quad*8 + 32];
      acc[c*4+j] = MFMA(qf0, kf0, acc[c*4+j]);
      acc[c*4+j] = MFMA(qf1, kf1, acc[c*4+j]);
    }
  }

  // per-wave partial stats over its 256 s-columns
  float mrow[4], lrow[4];
  #pragma unroll
  for (int r=0;r<4;r++){
    float m = acc[0][r];
    #pragma unroll
    for (int a=1;a<16;a++) m = fmaxf(m, acc[a][r]);
    #pragma unroll
    for (int off=1; off<16; off<<=1) m = fmaxf(m, __shfl_xor(m, off));
    float l = 0.f;
    #pragma unroll
    for (int a=0;a<16;a++) l += __expf(acc[a][r]-m);
    #pragma unroll
    for (int off=1; off<16; off<<=1) l += __shfl_xor(l, off);
    mrow[r]=m; lrow[r]=l;
  }
  if (l16==0){
    #pragma unroll
    for (int r=0;r<4;r++){
      pm[ws][wt*16+quad*4+r] = mrow[r];
      pl[ws][wt*16+quad*4+r] = lrow[r];
    }
  }
  __syncthreads();
  if (tid < 64){
    float m0s = pm[0][tid], m1s = pm[1][tid], m2s = pm[2][tid], m3s = pm[3][tid];
    float m = fmaxf(fmaxf(m0s,m1s), fmaxf(m2s,m3s));
    float l = pl[0][tid]*__expf(m0s-m) + pl[1][tid]*__expf(m1s-m)
            + pl[2][tid]*__expf(m2s-m) + pl[3][tid]*__expf(m3s-m);
    fm[tid] = m;
    fr[tid] = beta[h*1024 + t0b + tid] / l;
  }
  __syncthreads();

  u16* Pp = P + (((size_t)b)<<24) + (((size_t)h)<<10);   // [b][t][h][s]
  float m_f[4], r_f[4]; int trow[4];
  #pragma unroll
  for (int r=0;r<4;r++){
    int rg = wt*16+quad*4+r;
    m_f[r] = fm[rg]; r_f[r] = fr[rg]; trow[r] = t0b + rg;
  }
  const int slim = tb*4 + wt;        // last s-tile with any s<=t (per-wave t-group)
  u16* Pb = ks;                      // bounce buffer, rows of 264
  const int srowP = tid>>4;          // 0..63 store row
  const int sgu = tid&15;            // 16-col store unit
  const int tglob = t0b + srowP;
  const int tmax = tglob|15;
  const int ncP = tb/4 + 1;          // live 256-chunks
  for (int c=0;c<ncP;c++){
    __syncthreads();
    #pragma unroll
    for (int j=0;j<4;j++){
      int st = c*16 + j*4 + ws;
      if (st > slim) continue;
      int s = st*16 + l16;
      int s_loc = (j*4+ws)*16 + l16;
      float av = als[s];
      #pragma unroll
      for (int r=0;r<4;r++){
        int t = trow[r], t_loc = wt*16 + quad*4 + r;
        float p = 0.f;
        if (s <= t)
          p = __expf(acc[c*4+j][r]-m_f[r])*r_f[r]*tws[1023+s-t]*av;
        Pb[t_loc*264 + s_loc] = f2b(p);
      }
    }
    __syncthreads();
    int sg0 = c*256 + sgu*16;
    if (sg0 <= tmax){
      uint4 a0 = *(const uint4*)&Pb[srowP*264 + sgu*16];
      uint4 a1 = *(const uint4*)&Pb[srowP*264 + sgu*16 + 8];
      u16* dst = Pp + (((size_t)tglob)<<14) + sg0;
      *(uint4*)(dst)   = a0;
      *(uint4*)(dst+8) = a1;
    }
  }
}

// ---------------- head-mix: A[b][t][g][s] = sum_h Wmix[g][h] P[b][t][h][s] ----------------
// grid (1024 t, 2 b); 256 thr; per-t P slab staged by 256-col chunks into LDS
__global__ __launch_bounds__(256) void k_mix(const u16* __restrict__ P, const float* __restrict__ Wm,
                                             u16* __restrict__ Ab)
{
  const int t = blockIdx.x, b = blockIdx.y;
  const int tid = threadIdx.x;
  const int g = tid>>4, sg = tid&15;
  __shared__ u16 Ps[16*264];
  float w[16];
  #pragma unroll
  for (int h=0;h<16;h++) w[h] = Wm[g*16+h];
  const int tmaxr = t|15;             // P/A defined for s <= tmaxr
  const int ncw = (t>>8) + 1;
  const size_t slab = (((size_t)b)<<24) + (((size_t)t)<<14);
  const u16* pp = P + slab;
  u16* ap = Ab + slab;
  for (int c=0;c<ncw;c++){
    int s0 = c*256;
    if (c) __syncthreads();
    int colg = sg*16;
    uint4 z = {0u,0u,0u,0u};
    uint4 v0 = z, v1 = z;
    if (s0+colg <= tmaxr){
      v0 = *(const uint4*)(pp + ((size_t)g<<10) + s0+colg);
      v1 = *(const uint4*)(pp + ((size_t)g<<10) + s0+colg+8);
    }
    *(uint4*)&Ps[g*264+colg]   = v0;
    *(uint4*)&Ps[g*264+colg+8] = v1;
    __syncthreads();
    if (s0 + sg*16 > tmaxr) continue;      // A beyond t|15 never read (k_pv zero-predicates)
    float acc[16];
    #pragma unroll
    for (int i=0;i<16;i++) acc[i]=0.f;
    #pragma unroll
    for (int h=0;h<16;h++){
      float wh = w[h];
      #pragma unroll
      for (int j=0;j<4;j++){
        ushort4 u = *(const ushort4*)&Ps[h*264 + sg*16 + j*4];
        acc[j*4+0] += wh*b2f(u.x);
        acc[j*4+1] += wh*b2f(u.y);
        acc[j*4+2] += wh*b2f(u.z);
        acc[j*4+3] += wh*b2f(u.w);
      }
    }
    u16 o[16];
    #pragma unroll
    for (int i=0;i<16;i++) o[i] = f2b(acc[i]);
    *(uint4*)(ap + ((size_t)g<<10) + s0 + sg*16)     = *(uint4*)&o[0];
    *(uint4*)(ap + ((size_t)g<<10) + s0 + sg*16 + 8) = *(uint4*)&o[8];
  }
}

// ---------------- PV: grid (tb=16, bg=32); 16 waves = 4 wt x 4 wd; LDS-staged s-chunks ----------------
__global__ __launch_bounds__(1024) void k_pv(const u16* __restrict__ Ab, const u16* __restrict__ vT,
                                             u16* __restrict__ y)
{
  const int tb = blockIdx.x;          // 0..15
  const int bg = blockIdx.y;          // 0..31 = b*16+g
  const int b = bg>>4, g = bg&15;
  const int t0b = tb*64;
  const int tid = threadIdx.x;
  const int wave = tid>>6, lane = tid&63, quad = lane>>4, l16 = lane&15;
  const int wt = wave>>2, wd = wave&3;
  __shared__ u16 As[64*264];
  __shared__ u16 Vs[64*264];
  const u16* ap = Ab + (((size_t)b)<<24) + ((size_t)g<<10);   // [b][t][g][s]
  const u16* vp = vT + (size_t)bg*65536;   // [d][t]
  f32x4 acc = {0.f,0.f,0.f,0.f};
  const int nc = tb/4 + 1;            // causal: only chunks with s0 <= t|63
  const int row = tid>>4, col = (tid&15)*16;
  const int trow_g = t0b + row;
  const int tmax = trow_g|15;         // A defined only to here
  for (int c=0;c<nc;c++){
    if (c) __syncthreads();
    int s0 = c*256;
    uint4 z = {0u,0u,0u,0u};
    uint4 a0 = z, a1 = z;
    if (s0 + col <= tmax){
      a0 = *(const uint4*)(ap + ((size_t)trow_g<<14) + s0+col);
      a1 = *(const uint4*)(ap + ((size_t)trow_g<<14) + s0+col+8);
    }
    *(uint4*)&As[row*264+col]   = a0;
    *(uint4*)&As[row*264+col+8] = a1;
    *(uint4*)&Vs[row*264+col]   = *(const uint4*)(vp + (size_t)row*1024 + s0+col);
    *(uint4*)&Vs[row*264+col+8] = *(const uint4*)(vp + (size_t)row*1024 + s0+col+8);
    __syncthreads();
    #pragma unroll
    for (int ks=0;ks<8;ks++){
      bf16x8 af  = *(const bf16x8*)&As[(wt*16+l16)*264 + ks*32 + quad*8];
      bf16x8 bfv = *(const bf16x8*)&Vs[(wd*16+l16)*264 + ks*32 + quad*8];
      acc = MFMA(af, bfv, acc);
    }
  }
  #pragma unroll
  for (int r=0;r<4;r++){
    int t = t0b + wt*16 + quad*4 + r;
    y[(size_t)(b*1024+t)*1024 + g*64 + wd*16 + l16] = f2b(acc[r]);
  }
}

__global__ void k_fail(float* out){ if (threadIdx.x==0) out[0] = 1e30f; } // ws-too-small marker

extern "C" void kernel_launch(void* const* d_in, const int* in_sizes, int n_in,
                              void* d_out, int out_size, void* d_ws, size_t ws_size,
                              hipStream_t stream)
{
  const float* x     = (const float*)d_in[0];
  const float* tw    = (const float*)d_in[1];
  const float* alpha = (const float*)d_in[2];
  const float* beta  = (const float*)d_in[3];
  const float* gamma = (const float*)d_in[4];
  const float* Wq    = (const float*)d_in[5];
  const float* bq    = (const float*)d_in[6];
  const float* Wk    = (const float*)d_in[7];
  const float* bk    = (const float*)d_in[8];
  const float* Wv    = (const float*)d_in[9];
  const float* bv    = (const float*)d_in[10];
  const float* Wmix  = (const float*)d_in[11];
  const float* Wo    = (const float*)d_in[12];
  const float* bo    = (const float*)d_in[13];
  float* out = (float*)d_out;

  char* ws = (char*)d_ws;
  size_t off = 0;
  auto take = [&](size_t bytes)->char*{
    char* p = ws + off; off += (bytes + 255) & ~(size_t)255; return p;
  };
  u16*   xs  = (u16*)take((size_t)2097152*2);   // xs (B*T, C) bf16
  u16*   WT  = (u16*)take((size_t)3145728*2);   // [3072][1024] = Wq^T|Wk^T|Wv^T bf16
  u16*   WoT = (u16*)take((size_t)1048576*2);
  u16*   qb  = (u16*)take((size_t)2097152*2);   // (b,h,t,d) rope'd, x1/8
  u16*   kb  = (u16*)take((size_t)2097152*2);   // (b,h,t,d) rope'd
  u16*   vTb = (u16*)take((size_t)2097152*2);   // (b,h,d,t)
  u16*   yb  = (u16*)take((size_t)2097152*2);   // (b,t,g,d)
  u16*   P   = (u16*)take((size_t)33554432*2);  // [b][t][h][s]
  u16*   A   = (u16*)take((size_t)33554432*2);  // [b][t][g][s]
  if (off > ws_size){
    hipLaunchKernelGGL(k_fail, dim3(1), dim3(64), 0, stream, out);
    return;
  }

  hipLaunchKernelGGL(k_pre, dim3(2048), dim3(256), 0, stream,
                     x, Wq, Wk, Wv, Wo, xs, WT, WoT);
  hipLaunchKernelGGL(k_gemm_qkv, dim3(48,16), dim3(256), 0, stream,
                     xs, WT, bq, bk, bv, qb, kb, vTb);
  hipLaunchKernelGGL(k_sm, dim3(16,16,2), dim3(1024), 0, stream,
                     qb, kb, tw, alpha, beta, P);
  hipLaunchKernelGGL(k_mix, dim3(1024,2), dim3(256), 0, stream, P, Wmix, A);
  hipLaunchKernelGGL(k_pv, dim3(16,32), dim3(1024), 0, stream, A, vTb, yb);
  hipLaunchKernelGGL(k_gemm_out, dim3(16,32), dim3(256), 0, stream, yb, WoT, bo, gamma, out);
}

// Round 11
// 208.171 us; speedup vs baseline: 1.3467x; 1.3467x over previous
//
#include <hip/hip_runtime.h>

typedef unsigned short u16;
typedef unsigned int u32;
typedef __attribute__((ext_vector_type(8))) short bf16x8;
typedef __attribute__((ext_vector_type(4))) float f32x4;

#define MFMA(a,b,c) __builtin_amdgcn_mfma_f32_16x16x32_bf16(a,b,c,0,0,0)

__device__ __forceinline__ float b2f(u16 u){
  union { unsigned int i; float f; } v; v.i = ((unsigned int)u)<<16; return v.f;
}
__device__ __forceinline__ u16 f2b(float f){
  union { float f; unsigned int i; } v; v.f = f;
  unsigned int r = (v.i + 0x7FFFu + ((v.i>>16)&1u))>>16;
  return (u16)r;
}
// async global->LDS, 16B per lane; lds dest must be wave-uniform base (HW adds lane*16)
__device__ __forceinline__ void gld16(const u16* g, u16* l){
  __builtin_amdgcn_global_load_lds((const __attribute__((address_space(1))) u32*)g,
                                   (__attribute__((address_space(3))) u32*)l, 16, 0, 0);
}

// ---------------- combined: time-shift prep (blocks 0..1023) + 4 weight transposes ----------------
__global__ __launch_bounds__(256) void k_pre(
    const float* __restrict__ x,
    const float* __restrict__ Wq, const float* __restrict__ Wk,
    const float* __restrict__ Wv, const float* __restrict__ Wo,
    u16* __restrict__ xs, u16* __restrict__ WT, u16* __restrict__ WoT)
{
  int bid = blockIdx.x;
  int tid = threadIdx.x;
  if (bid < 1024){
    int idx = bid*256 + tid;                 // one thread per 8 elements
    size_t e = (size_t)idx*8;
    int c = (int)(e & 1023);
    int t = (int)((e>>10)&1023);
    float4 f0 = {0.f,0.f,0.f,0.f}, f1 = {0.f,0.f,0.f,0.f};
    const float* src = nullptr;
    if (c < 512){ if (t > 0) src = x + e - 1024; }
    else        { src = x + e; }
    if (src){ f0 = *(const float4*)src; f1 = *(const float4*)(src+4); }
    u16 o[8];
    o[0]=f2b(f0.x); o[1]=f2b(f0.y); o[2]=f2b(f0.z); o[3]=f2b(f0.w);
    o[4]=f2b(f1.x); o[5]=f2b(f1.y); o[6]=f2b(f1.z); o[7]=f2b(f1.w);
    *(uint4*)(xs + e) = *(const uint4*)o;
    return;
  }
  int z  = (bid-1024)>>8;                    // 0..3 : Wq,Wk,Wv,Wo
  int rc = (bid-1024)&255;
  const float* src = (z==0)?Wq:((z==1)?Wk:((z==2)?Wv:Wo));
  u16* dst = (z==3)? WoT : (WT + (size_t)z*1048576);
  int c0 = (rc&15)*64, r0 = (rc>>4)*64;
  __shared__ u16 tile[64][72];
  int r = tid>>2, cc = (tid&3)*16;
  const float* sp = src + (size_t)(r0+r)*1024 + c0+cc;
  float4 a0 = *(const float4*)(sp);
  float4 a1 = *(const float4*)(sp+4);
  float4 a2 = *(const float4*)(sp+8);
  float4 a3 = *(const float4*)(sp+12);
  tile[r][cc+0]=f2b(a0.x); tile[r][cc+1]=f2b(a0.y); tile[r][cc+2]=f2b(a0.z); tile[r][cc+3]=f2b(a0.w);
  tile[r][cc+4]=f2b(a1.x); tile[r][cc+5]=f2b(a1.y); tile[r][cc+6]=f2b(a1.z); tile[r][cc+7]=f2b(a1.w);
  tile[r][cc+8]=f2b(a2.x); tile[r][cc+9]=f2b(a2.y); tile[r][cc+10]=f2b(a2.z); tile[r][cc+11]=f2b(a2.w);
  tile[r][cc+12]=f2b(a3.x); tile[r][cc+13]=f2b(a3.y); tile[r][cc+14]=f2b(a3.z); tile[r][cc+15]=f2b(a3.w);
  __syncthreads();
  int c = tid>>2, rr = (tid&3)*16;
  uint4 o0,o1; u16* p0=(u16*)&o0; u16* p1=(u16*)&o1;
  #pragma unroll
  for (int i=0;i<8;i++){ p0[i]=tile[rr+i][c]; p1[i]=tile[rr+8+i][c]; }
  *(uint4*)(dst + (size_t)(c0+c)*1024 + r0+rr)   = o0;
  *(uint4*)(dst + (size_t)(c0+c)*1024 + r0+rr+8) = o1;
}

// ---------------- QKV GEMM 128x64 tiles (global_load_lds) + fused RoPE; v -> (b,h,d,t) ----------------
// grid (48, 16): n0=bx*64 (64-aligned => which,h uniform per block)
__global__ __launch_bounds__(256) void k_gemm_qkv(
    const u16* __restrict__ A, const u16* __restrict__ Bt,
    const float* __restrict__ bq, const float* __restrict__ bk, const float* __restrict__ bv,
    u16* __restrict__ qb, u16* __restrict__ kb, u16* __restrict__ vT)
{
  __shared__ u16 As[128*32];     // unpadded: required by global_load_lds lane order
  __shared__ u16 Bs[64*32];
  const int n0 = blockIdx.x*64, m0 = blockIdx.y*128;
  const int tid = threadIdx.x, lane = tid&63, wave = tid>>6;
  const int quad = lane>>4, l16 = lane&15;
  const int wm = (wave>>1)*64, wn = (wave&1)*32;
  f32x4 zero = {0.f,0.f,0.f,0.f};
  f32x4 acc[4][2];
  #pragma unroll
  for (int i=0;i<4;i++){ acc[i][0]=zero; acc[i][1]=zero; }
  const int srow = (lane>>2), scol = (lane&3)*8;
  const u16* pa0 = A  + (size_t)(m0 + wave*16 + srow)*1024 + scol;
  const u16* pb0 = Bt + (size_t)(n0 + wave*16 + srow)*1024 + scol;
  u16* lA0 = &As[(wave*16)*32];
  u16* lA1 = &As[(64 + wave*16)*32];
  u16* lB0 = &Bs[(wave*16)*32];
  for (int k0=0;k0<1024;k0+=32){
    __syncthreads();
    gld16(pa0 + k0,           lA0);
    gld16(pa0 + 64*1024 + k0, lA1);
    gld16(pb0 + k0,           lB0);
    __syncthreads();
    bf16x8 af[4], bfr[2];
    #pragma unroll
    for (int mt=0;mt<4;mt++) af[mt]  = *(const bf16x8*)&As[(wm+mt*16+l16)*32 + quad*8];
    #pragma unroll
    for (int nt=0;nt<2;nt++) bfr[nt] = *(const bf16x8*)&Bs[(wn+nt*16+l16)*32 + quad*8];
    #pragma unroll
    for (int mt=0;mt<4;mt++){
      acc[mt][0] = MFMA(af[mt], bfr[0], acc[mt][0]);
      acc[mt][1] = MFMA(af[mt], bfr[1], acc[mt][1]);
    }
  }
  const int which = n0>>10;            // uniform per block
  const int nn0 = (n0 & 1023) + wn;
  const int h = (n0 & 1023)>>6;
  const float* barr = (which==0)?bq:((which==1)?bk:bv);
  float bias0 = barr[nn0 + l16];
  float bias1 = barr[nn0 + 16 + l16];
  if (which == 2){
    // v: write transposed (b,h,d,t): vT[bh*65536 + d*1024 + t]
    #pragma unroll
    for (int mt=0;mt<4;mt++)
      #pragma unroll
      for (int r=0;r<4;r++){
        int m = m0 + wm + mt*16 + quad*4 + r;
        int bb = m>>10, t = m&1023;
        size_t base = (size_t)(bb*16+h)*65536 + t;
        int d0 = wn + l16;
        vT[base + (size_t)d0*1024]      = f2b(acc[mt][0][r] + bias0);
        vT[base + (size_t)(d0+16)*1024] = f2b(acc[mt][1][r] + bias1);
      }
  } else {
    const float scale = (which==0)?0.125f:1.0f;
    u16* dst = (which==0)? qb : kb;
    if (wn == 0){
      const float e = exp2f(-0.625f*(float)l16);
      #pragma unroll
      for (int mt=0;mt<4;mt++)
        #pragma unroll
        for (int r=0;r<4;r++){
          int m = m0 + wm + mt*16 + quad*4 + r;
          int bb = m>>10, t = m&1023;
          float f = (float)t * e;
          float cs = cosf(f), sn = sinf(f);
          float x0 = acc[mt][0][r] + bias0;
          float x1 = acc[mt][1][r] + bias1;
          float v0 = (x0*cs - x1*sn)*scale;
          float v1 = (x1*cs + x0*sn)*scale;
          size_t ob = (((size_t)(bb*16+h))*1024 + (size_t)t)*64 + l16;
          dst[ob]    = f2b(v0);
          dst[ob+16] = f2b(v1);
        }
    } else {
      #pragma unroll
      for (int mt=0;mt<4;mt++)
        #pragma unroll
        for (int r=0;r<4;r++){
          int m = m0 + wm + mt*16 + quad*4 + r;
          int bb = m>>10, t = m&1023;
          float v2 = (acc[mt][0][r] + bias0)*scale;
          float v3 = (acc[mt][1][r] + bias1)*scale;
          size_t ob = (((size_t)(bb*16+h))*1024 + (size_t)t)*64 + 32 + l16;
          dst[ob]    = f2b(v2);
          dst[ob+16] = f2b(v3);
        }
    }
  }
}

// ---------------- output GEMM 64x64 tiles: + bo, x gamma[t], f32 out ----------------
// grid (16, 32) = 512 blocks (2/CU for inter-block overlap)
__global__ __launch_bounds__(256) void k_gemm_out(
    const u16* __restrict__ A, const u16* __restrict__ Bt,
    const float* __restrict__ bo, const float* __restrict__ gamma, float* __restrict__ out)
{
  __shared__ u16 As[64*32];
  __shared__ u16 Bs[64*32];
  const int n0 = blockIdx.x*64, m0 = blockIdx.y*64;
  const int tid = threadIdx.x, lane = tid&63, wave = tid>>6;
  const int quad = lane>>4, l16 = lane&15;
  const int wm = (wave>>1)*32, wn = (wave&1)*32;
  f32x4 zero = {0.f,0.f,0.f,0.f};
  f32x4 acc[2][2];
  #pragma unroll
  for (int i=0;i<2;i++){ acc[i][0]=zero; acc[i][1]=zero; }
  const int srow = (lane>>2), scol = (lane&3)*8;
  const u16* pa0 = A  + (size_t)(m0 + wave*16 + srow)*1024 + scol;
  const u16* pb0 = Bt + (size_t)(n0 + wave*16 + srow)*1024 + scol;
  u16* lA0 = &As[(wave*16)*32];
  u16* lB0 = &Bs[(wave*16)*32];
  for (int k0=0;k0<1024;k0+=32){
    __syncthreads();
    gld16(pa0 + k0, lA0);
    gld16(pb0 + k0, lB0);
    __syncthreads();
    bf16x8 af[2], bfr[2];
    #pragma unroll
    for (int mt=0;mt<2;mt++) af[mt]  = *(const bf16x8*)&As[(wm+mt*16+l16)*32 + quad*8];
    #pragma unroll
    for (int nt=0;nt<2;nt++) bfr[nt] = *(const bf16x8*)&Bs[(wn+nt*16+l16)*32 + quad*8];
    #pragma unroll
    for (int mt=0;mt<2;mt++){
      acc[mt][0] = MFMA(af[mt], bfr[0], acc[mt][0]);
      acc[mt][1] = MFMA(af[mt], bfr[1], acc[mt][1]);
    }
  }
  #pragma unroll
  for (int nt=0;nt<2;nt++){
    int colg = n0 + wn + nt*16 + l16;
    float bias = bo[colg];
    #pragma unroll
    for (int mt=0;mt<2;mt++)
      #pragma unroll
      for (int r=0;r<4;r++){
        int m = m0 + wm + mt*16 + quad*4 + r;
        int t = m&1023;
        float val = (acc[mt][nt][r] + bias)*gamma[t];
        out[(size_t)m*1024 + colg] = val;
      }
  }
}

// ---------------- fused softmax+weight: S in registers, stats in LDS, write P ----------------
// grid (tb=16, h=16, b=2); 1024 threads = 16 waves = 4 wt x 4 ws; full 64t x 1024s S tile in regs
// P layout: [b][t][h][s] -- direct scattered stores (proven: L2 write-combines these fine)
__global__ __launch_bounds__(1024) void k_sm(
    const u16* __restrict__ q, const u16* __restrict__ k,
    const float* __restrict__ tw, const float* __restrict__ alpha, const float* __restrict__ beta,
    u16* __restrict__ P)
{
  const int tb = blockIdx.x, h = blockIdx.y, b = blockIdx.z;
  const int t0b = tb*64;
  const int tid = threadIdx.x;
  const int wave = tid>>6, lane = tid&63, quad = lane>>4, l16 = lane&15;
  const int wt = wave>>2, ws = wave&3;

  __shared__ u16 qs[64*76];      // q tile, padded rows
  __shared__ u16 ks[256*76];     // K chunk, padded rows
  __shared__ float tws[1024];
  __shared__ float als[1024];
  __shared__ float pm[4][64];
  __shared__ float pl[4][64];
  __shared__ float fm[64];
  __shared__ float fr[64];

  const size_t bh = (size_t)(b*16+h)*65536;
  const u16* qp = q + bh;
  const u16* kp = k + bh;

  if (tid < 512){
    int row = tid>>3, g = tid&7;
    *(uint4*)&qs[row*76 + g*8] = *(const uint4*)(qp + (size_t)(t0b+row)*64 + g*8);
  }
  tws[tid] = tw[h*1024 + tid];
  als[tid] = alpha[h*1024 + tid];
  __syncthreads();

  bf16x8 qf0 = *(const bf16x8*)&qs[(wt*16+l16)*76 + quad*8];
  bf16x8 qf1 = *(const bf16x8*)&qs[(wt*16+l16)*76 + quad*8 + 32];

  f32x4 acc[16];
  #pragma unroll
  for (int i=0;i<16;i++){ acc[i][0]=0.f; acc[i][1]=0.f; acc[i][2]=0.f; acc[i][3]=0.f; }

  #pragma unroll
  for (int c=0;c<4;c++){
    if (c) __syncthreads();
    {
      int row = tid>>3, g = tid&7;
      *(uint4*)&ks[row*76 + g*8]       = *(const uint4*)(kp + (size_t)(c*256+row)*64 + g*8);
      *(uint4*)&ks[(row+128)*76 + g*8] = *(const uint4*)(kp + (size_t)(c*256+row+128)*64 + g*8);
    }
    __syncthreads();
    #pragma unroll
    for (int j=0;j<4;j++){
      int lt = j*4 + ws;
      bf16x8 kf0 = *(const bf16x8*)&ks[(lt*16+l16)*76 + quad*8];
      bf16x8 kf1 = *(const bf16x8*)&ks[(lt*16+l16)*76 + quad*8 + 32];
      acc[c*4+j] = MFMA(qf0, kf0, acc[c*4+j]);
      acc[c*4+j] = MFMA(qf1, kf1, acc[c*4+j]);
    }
  }

  // per-wave partial stats over its 256 s-columns
  float mrow[4], lrow[4];
  #pragma unroll
  for (int r=0;r<4;r++){
    float m = acc[0][r];
    #pragma unroll
    for (int a=1;a<16;a++) m = fmaxf(m, acc[a][r]);
    #pragma unroll
    for (int off=1; off<16; off<<=1) m = fmaxf(m, __shfl_xor(m, off));
    float l = 0.f;
    #pragma unroll
    for (int a=0;a<16;a++) l += __expf(acc[a][r]-m);
    #pragma unroll
    for (int off=1; off<16; off<<=1) l += __shfl_xor(l, off);
    mrow[r]=m; lrow[r]=l;
  }
  if (l16==0){
    #pragma unroll
    for (int r=0;r<4;r++){
      pm[ws][wt*16+quad*4+r] = mrow[r];
      pl[ws][wt*16+quad*4+r] = lrow[r];
    }
  }
  __syncthreads();
  if (tid < 64){
    float m0s = pm[0][tid], m1s = pm[1][tid], m2s = pm[2][tid], m3s = pm[3][tid];
    float m = fmaxf(fmaxf(m0s,m1s), fmaxf(m2s,m3s));
    float l = pl[0][tid]*__expf(m0s-m) + pl[1][tid]*__expf(m1s-m)
            + pl[2][tid]*__expf(m2s-m) + pl[3][tid]*__expf(m3s-m);
    fm[tid] = m;
    fr[tid] = beta[h*1024 + t0b + tid] / l;
  }
  __syncthreads();

  u16* Pp = P + (((size_t)b)<<24) + (((size_t)h)<<10);   // [b][t][h][s]
  float m_f[4], r_f[4]; int trow[4];
  #pragma unroll
  for (int r=0;r<4;r++){
    int rg = wt*16+quad*4+r;
    m_f[r] = fm[rg]; r_f[r] = fr[rg]; trow[r] = t0b + rg;
  }
  const int slim = tb*4 + wt;   // last s-tile with any s<=t
  #pragma unroll
  for (int c=0;c<4;c++)
    #pragma unroll
    for (int j=0;j<4;j++){
      int st = c*16 + j*4 + ws;
      if (st > slim) continue;
      int s = st*16 + l16;
      float av = als[s];
      #pragma unroll
      for (int r=0;r<4;r++){
        int t = trow[r];
        float p = 0.f;
        if (s <= t)
          p = __expf(acc[c*4+j][r]-m_f[r])*r_f[r]*tws[1023+s-t]*av;
        Pp[((size_t)t<<14) + s] = f2b(p);
      }
    }
}

// ---------------- head-mix: A[b][t][g][s] = sum_h Wmix[g][h] P[b][t][h][s] ----------------
// grid (1024 t, 2 b); 256 thr; per-t P slab staged by 256-col chunks into LDS
__global__ __launch_bounds__(256) void k_mix(const u16* __restrict__ P, const float* __restrict__ Wm,
                                             u16* __restrict__ Ab)
{
  const int t = blockIdx.x, b = blockIdx.y;
  const int tid = threadIdx.x;
  const int g = tid>>4, sg = tid&15;
  __shared__ u16 Ps[16*264];
  float w[16];
  #pragma unroll
  for (int h=0;h<16;h++) w[h] = Wm[g*16+h];
  const int tmaxr = t|15;             // P/A defined for s <= tmaxr
  const int ncw = (t>>8) + 1;
  const size_t slab = (((size_t)b)<<24) + (((size_t)t)<<14);
  const u16* pp = P + slab;
  u16* ap = Ab + slab;
  for (int c=0;c<ncw;c++){
    int s0 = c*256;
    if (c) __syncthreads();
    int colg = sg*16;
    uint4 z = {0u,0u,0u,0u};
    uint4 v0 = z, v1 = z;
    if (s0+colg <= tmaxr){
      v0 = *(const uint4*)(pp + ((size_t)g<<10) + s0+colg);
      v1 = *(const uint4*)(pp + ((size_t)g<<10) + s0+colg+8);
    }
    *(uint4*)&Ps[g*264+colg]   = v0;
    *(uint4*)&Ps[g*264+colg+8] = v1;
    __syncthreads();
    if (s0 + sg*16 > tmaxr) continue;      // A beyond t|15 never read (k_pv zero-predicates)
    float acc[16];
    #pragma unroll
    for (int i=0;i<16;i++) acc[i]=0.f;
    #pragma unroll
    for (int h=0;h<16;h++){
      float wh = w[h];
      #pragma unroll
      for (int j=0;j<4;j++){
        ushort4 u = *(const ushort4*)&Ps[h*264 + sg*16 + j*4];
        acc[j*4+0] += wh*b2f(u.x);
        acc[j*4+1] += wh*b2f(u.y);
        acc[j*4+2] += wh*b2f(u.z);
        acc[j*4+3] += wh*b2f(u.w);
      }
    }
    u16 o[16];
    #pragma unroll
    for (int i=0;i<16;i++) o[i] = f2b(acc[i]);
    *(uint4*)(ap + ((size_t)g<<10) + s0 + sg*16)     = *(uint4*)&o[0];
    *(uint4*)(ap + ((size_t)g<<10) + s0 + sg*16 + 8) = *(uint4*)&o[8];
  }
}

// ---------------- PV: grid (tb=16, bg=32); 16 waves = 4 wt x 4 wd; LDS-staged s-chunks ----------------
__global__ __launch_bounds__(1024) void k_pv(const u16* __restrict__ Ab, const u16* __restrict__ vT,
                                             u16* __restrict__ y)
{
  const int tb = blockIdx.x;          // 0..15
  const int bg = blockIdx.y;          // 0..31 = b*16+g
  const int b = bg>>4, g = bg&15;
  const int t0b = tb*64;
  const int tid = threadIdx.x;
  const int wave = tid>>6, lane = tid&63, quad = lane>>4, l16 = lane&15;
  const int wt = wave>>2, wd = wave&3;
  __shared__ u16 As[64*264];
  __shared__ u16 Vs[64*264];
  const u16* ap = Ab + (((size_t)b)<<24) + ((size_t)g<<10);   // [b][t][g][s]
  const u16* vp = vT + (size_t)bg*65536;   // [d][t]
  f32x4 acc = {0.f,0.f,0.f,0.f};
  const int nc = tb/4 + 1;            // causal: only chunks with s0 <= t|63
  const int row = tid>>4, col = (tid&15)*16;
  const int trow_g = t0b + row;
  const int tmax = trow_g|15;         // A defined only to here
  for (int c=0;c<nc;c++){
    if (c) __syncthreads();
    int s0 = c*256;
    uint4 z = {0u,0u,0u,0u};
    uint4 a0 = z, a1 = z;
    if (s0 + col <= tmax){
      a0 = *(const uint4*)(ap + ((size_t)trow_g<<14) + s0+col);
      a1 = *(const uint4*)(ap + ((size_t)trow_g<<14) + s0+col+8);
    }
    *(uint4*)&As[row*264+col]   = a0;
    *(uint4*)&As[row*264+col+8] = a1;
    *(uint4*)&Vs[row*264+col]   = *(const uint4*)(vp + (size_t)row*1024 + s0+col);
    *(uint4*)&Vs[row*264+col+8] = *(const uint4*)(vp + (size_t)row*1024 + s0+col+8);
    __syncthreads();
    #pragma unroll
    for (int ks=0;ks<8;ks++){
      bf16x8 af  = *(const bf16x8*)&As[(wt*16+l16)*264 + ks*32 + quad*8];
      bf16x8 bfv = *(const bf16x8*)&Vs[(wd*16+l16)*264 + ks*32 + quad*8];
      acc = MFMA(af, bfv, acc);
    }
  }
  #pragma unroll
  for (int r=0;r<4;r++){
    int t = t0b + wt*16 + quad*4 + r;
    y[(size_t)(b*1024+t)*1024 + g*64 + wd*16 + l16] = f2b(acc[r]);
  }
}

__global__ void k_fail(float* out){ if (threadIdx.x==0) out[0] = 1e30f; } // ws-too-small marker

extern "C" void kernel_launch(void* const* d_in, const int* in_sizes, int n_in,
                              void* d_out, int out_size, void* d_ws, size_t ws_size,
                              hipStream_t stream)
{
  const float* x     = (const float*)d_in[0];
  const float* tw    = (const float*)d_in[1];
  const float* alpha = (const float*)d_in[2];
  const float* beta  = (const float*)d_in[3];
  const float* gamma = (const float*)d_in[4];
  const float* Wq    = (const float*)d_in[5];
  const float* bq    = (const float*)d_in[6];
  const float* Wk    = (const float*)d_in[7];
  const float* bk    = (const float*)d_in[8];
  const float* Wv    = (const float*)d_in[9];
  const float* bv    = (const float*)d_in[10];
  const float* Wmix  = (const float*)d_in[11];
  const float* Wo    = (const float*)d_in[12];
  const float* bo    = (const float*)d_in[13];
  float* out = (float*)d_out;

  char* ws = (char*)d_ws;
  size_t off = 0;
  auto take = [&](size_t bytes)->char*{
    char* p = ws + off; off += (bytes + 255) & ~(size_t)255; return p;
  };
  u16*   xs  = (u16*)take((size_t)2097152*2);   // xs (B*T, C) bf16
  u16*   WT  = (u16*)take((size_t)3145728*2);   // [3072][1024] = Wq^T|Wk^T|Wv^T bf16
  u16*   WoT = (u16*)take((size_t)1048576*2);
  u16*   qb  = (u16*)take((size_t)2097152*2);   // (b,h,t,d) rope'd, x1/8
  u16*   kb  = (u16*)take((size_t)2097152*2);   // (b,h,t,d) rope'd
  u16*   vTb = (u16*)take((size_t)2097152*2);   // (b,h,d,t)
  u16*   yb  = (u16*)take((size_t)2097152*2);   // (b,t,g,d)
  u16*   P   = (u16*)take((size_t)33554432*2);  // [b][t][h][s]
  u16*   A   = (u16*)take((size_t)33554432*2);  // [b][t][g][s]
  if (off > ws_size){
    hipLaunchKernelGGL(k_fail, dim3(1), dim3(64), 0, stream, out);
    return;
  }

  hipLaunchKernelGGL(k_pre, dim3(2048), dim3(256), 0, stream,
                     x, Wq, Wk, Wv, Wo, xs, WT, WoT);
  hipLaunchKernelGGL(k_gemm_qkv, dim3(48,16), dim3(256), 0, stream,
                     xs, WT, bq, bk, bv, qb, kb, vTb);
  hipLaunchKernelGGL(k_sm, dim3(16,16,2), dim3(1024), 0, stream,
                     qb, kb, tw, alpha, beta, P);
  hipLaunchKernelGGL(k_mix, dim3(1024,2), dim3(256), 0, stream, P, Wmix, A);
  hipLaunchKernelGGL(k_pv, dim3(16,32), dim3(1024), 0, stream, A, vTb, yb);
  hipLaunchKernelGGL(k_gemm_out, dim3(16,32), dim3(256), 0, stream, yb, WoT, bo, gamma, out);
}